// Round 20
// baseline (188.431 us; speedup 1.0000x reference)
//
#include <hip/hip_runtime.h>
#include <stdint.h>

// r20: pv v8 = v6's counted-vmcnt pipeline at 128x128 / 4 waves / 64KB LDS
// -> 2 blocks/CU so block A's C-write overlaps block B's compute (the ~42us
// serial write identified in r19's ledger decomposition). Same vmcnt skeleton,
// same K-order (bit-identical). qk v9 + prep byte-identical to r19.
// Ledger: pv = dur - 54 (qk 49 + prep 5).

// ---------- types ----------
typedef __bf16 bf16x8 __attribute__((ext_vector_type(8)));
typedef unsigned short u16x8 __attribute__((ext_vector_type(8)));
typedef float f32x4 __attribute__((ext_vector_type(4)));

#define SM_SCALE 4.419417382415922e-02f /* 1/22.627416997969522 */
#define DROP_SCALE (1.0f / 0.9f)

// ---------- helpers ----------
__device__ __forceinline__ unsigned short f2bf(float f) {
  uint32_t u = __float_as_uint(f);
  uint32_t r = (u + 0x7FFFu + ((u >> 16) & 1u)) >> 16;  // RNE
  return (unsigned short)r;
}
__device__ __forceinline__ float bf2f(unsigned short h) {
  return __uint_as_float(((uint32_t)h) << 16);
}

// async global->LDS, 16B/lane. LDS dest = wave-uniform base + lane*16.
__device__ __forceinline__ void async16(const void* g, void* l) {
  __builtin_amdgcn_global_load_lds(
      (__attribute__((address_space(1))) uint32_t*)g,
      (__attribute__((address_space(3))) uint32_t*)l, 16, 0, 0);
}

// JAX threefry2x32 with key (0,42). [validated r4]
__device__ __forceinline__ void threefry2x32(uint32_t x0, uint32_t x1,
                                             uint32_t& o0, uint32_t& o1) {
  const uint32_t K0 = 0u, K1 = 42u;
  const uint32_t K2 = K0 ^ K1 ^ 0x1BD11BDAu;
  x0 += K0; x1 += K1;
#define TF_R(rot) { x0 += x1; x1 = (x1 << rot) | (x1 >> (32 - rot)); x1 ^= x0; }
  TF_R(13) TF_R(15) TF_R(26) TF_R(6)  x0 += K1; x1 += K2 + 1u;
  TF_R(17) TF_R(29) TF_R(16) TF_R(24) x0 += K2; x1 += K0 + 2u;
  TF_R(13) TF_R(15) TF_R(26) TF_R(6)  x0 += K0; x1 += K1 + 3u;
  TF_R(17) TF_R(29) TF_R(16) TF_R(24) x0 += K1; x1 += K2 + 4u;
  TF_R(13) TF_R(15) TF_R(26) TF_R(6)  x0 += K2; x1 += K0 + 5u;
#undef TF_R
  o0 = x0; o1 = x1;
}

// keep-mask, JAX partitionable threefry, ctr=(0,idx), XOR-fold. [validated r4]
__device__ __forceinline__ bool drop_keep(uint32_t idx) {
  uint32_t o0, o1;
  threefry2x32(0u, idx, o0, o1);
  uint32_t bits = o0 ^ o1;
  float u = __uint_as_float((bits >> 9) | 0x3f800000u) - 1.0f;  // [0,1)
  return u < 0.9f;
}

// ---------- kernel 1: value[512][4096] f32 -> valueT[4096][512] bf16 [validated r4] ----
__global__ __launch_bounds__(256) void k_vt(const float* __restrict__ v,
                                            unsigned short* __restrict__ vt) {
  __shared__ float tile[32][33];
  const int nb = blockIdx.x;   // 0..127
  const int kb = blockIdx.y;   // 0..15
  const int tx = threadIdx.x & 31, ty = threadIdx.x >> 5;  // 32 x 8
#pragma unroll
  for (int yy = 0; yy < 4; ++yy) {
    int row = ty + yy * 8;
    tile[row][tx] = v[(size_t)(kb * 32 + row) * 4096 + nb * 32 + tx];
  }
  __syncthreads();
#pragma unroll
  for (int yy = 0; yy < 4; ++yy) {
    int row = ty + yy * 8;
    vt[(size_t)(nb * 32 + row) * 512 + kb * 32 + tx] = f2bf(tile[tx][row]);
  }
}

// ---------- kernel 1b: in2 f32 -> bf16 (RNE) [validated r9] ----------
__global__ __launch_bounds__(256) void k_cast(const float* __restrict__ src,
                                              unsigned short* __restrict__ dst,
                                              int n4) {
  int i = blockIdx.x * 256 + threadIdx.x;
  if (i >= n4) return;
  float4 v = reinterpret_cast<const float4*>(src)[i];
  ushort4 h;
  h.x = f2bf(v.x); h.y = f2bf(v.y); h.z = f2bf(v.z); h.w = f2bf(v.w);
  reinterpret_cast<ushort4*>(dst)[i] = h;
}

// ---------- kernel 2: QK^T (A-split bf16 MFMA, 2-term) + softmax + dropout -> P ----
// [v9 exact bytes — r19, measured 49us]
__global__ __launch_bounds__(512, 4) void k_qk(const float* __restrict__ in1,
                                               const unsigned short* __restrict__ B2,
                                               unsigned short* __restrict__ P) {
  __shared__ unsigned short lB[512][36];  // 36.9KB, 72B stride -> conflict-free
  __shared__ float redm[2][64], reds[2][64];

  const int tid = threadIdx.x;
  const int l = tid & 63, w = tid >> 6;
  const int wr = w >> 1, wc = w & 1;      // wave grid 4 x 2
  const int g = l >> 4, c16 = l & 15;
  const int brow = blockIdx.x * 64;

  int scol[4], ssub[4];
#pragma unroll
  for (int i = 0; i < 4; ++i) {
    int c = i * 512 + tid;
    scol[i] = c >> 2;
    ssub[i] = c & 3;
  }

  f32x4 acc[16] = {};
  u16x8 stB[4];

#pragma unroll
  for (int i = 0; i < 4; ++i)
    stB[i] = *reinterpret_cast<const u16x8*>(B2 + (size_t)scol[i] * 512 + ssub[i] * 8);

  for (int kt = 0; kt < 16; ++kt) {
    const int k0 = kt * 32;
#pragma unroll
    for (int i = 0; i < 4; ++i)
      *reinterpret_cast<u16x8*>(&lB[scol[i]][ssub[i] * 8]) = stB[i];
    const int arow = brow + wr * 16 + c16;
    float4 v0 = *reinterpret_cast<const float4*>(in1 + (size_t)arow * 512 + k0 + g * 8);
    float4 v1 = *reinterpret_cast<const float4*>(in1 + (size_t)arow * 512 + k0 + g * 8 + 4);
    bf16x8 ahi, alo;
    {
      float vv[8] = {v0.x, v0.y, v0.z, v0.w, v1.x, v1.y, v1.z, v1.w};
      unsigned short h[8], lo8[8];
#pragma unroll
      for (int e = 0; e < 8; ++e) {
        h[e] = f2bf(vv[e]);
        lo8[e] = f2bf(vv[e] - bf2f(h[e]));
      }
      ahi = *reinterpret_cast<const bf16x8*>(h);
      alo = *reinterpret_cast<const bf16x8*>(lo8);
    }
    __syncthreads();
    if (kt < 15) {
      const int kn = k0 + 32;
#pragma unroll
      for (int i = 0; i < 4; ++i)
        stB[i] = *reinterpret_cast<const u16x8*>(B2 + (size_t)scol[i] * 512 + kn + ssub[i] * 8);
    }
#pragma unroll
    for (int j = 0; j < 16; ++j) {
      const int col = wc * 256 + j * 16 + c16;
      bf16x8 bh = *reinterpret_cast<const bf16x8*>(&lB[col][g * 8]);
      acc[j] = __builtin_amdgcn_mfma_f32_16x16x32_bf16(ahi, bh, acc[j], 0, 0, 0);
      acc[j] = __builtin_amdgcn_mfma_f32_16x16x32_bf16(alo, bh, acc[j], 0, 0, 0);
    }
    __syncthreads();
  }

  const int rowbase = wr * 16 + g * 4;
  float mx[4] = {-3.4e38f, -3.4e38f, -3.4e38f, -3.4e38f};
#pragma unroll
  for (int j = 0; j < 16; ++j)
#pragma unroll
    for (int r = 0; r < 4; ++r) {
      acc[j][r] *= SM_SCALE;
      mx[r] = fmaxf(mx[r], acc[j][r]);
    }
#pragma unroll
  for (int s = 1; s < 16; s <<= 1)
#pragma unroll
    for (int r = 0; r < 4; ++r) mx[r] = fmaxf(mx[r], __shfl_xor(mx[r], s, 64));
  if (c16 == 0) {
#pragma unroll
    for (int r = 0; r < 4; ++r) redm[wc][rowbase + r] = mx[r];
  }
  __syncthreads();
  float rmax[4], sum[4] = {0.f, 0.f, 0.f, 0.f};
#pragma unroll
  for (int r = 0; r < 4; ++r)
    rmax[r] = fmaxf(redm[0][rowbase + r], redm[1][rowbase + r]);
#pragma unroll
  for (int j = 0; j < 16; ++j)
#pragma unroll
    for (int r = 0; r < 4; ++r) {
      float e = expf(acc[j][r] - rmax[r]);
      acc[j][r] = e;
      sum[r] += e;
    }
#pragma unroll
  for (int s = 1; s < 16; s <<= 1)
#pragma unroll
    for (int r = 0; r < 4; ++r) sum[r] += __shfl_xor(sum[r], s, 64);
  if (c16 == 0) {
#pragma unroll
    for (int r = 0; r < 4; ++r) reds[wc][rowbase + r] = sum[r];
  }
  __syncthreads();
  float scl[4];
#pragma unroll
  for (int r = 0; r < 4; ++r)
    scl[r] = DROP_SCALE / (reds[0][rowbase + r] + reds[1][rowbase + r]);

#pragma unroll
  for (int j = 0; j < 16; ++j) {
    const int col = wc * 256 + j * 16 + c16;
#pragma unroll
    for (int r = 0; r < 4; ++r) {
      uint32_t idx = (uint32_t)(brow + rowbase + r) * 512u + (uint32_t)col;
      float pv = drop_keep(idx) ? acc[j][r] * scl[r] : 0.0f;
      P[idx] = f2bf(pv);
    }
  }
}

// ---------- kernel 3: out = P[16384][512] @ vT[4096][512]^T (bf16 MFMA) ----------
// v8: 128x128, 4 waves (2x2), counted-vmcnt k-half pipeline, 64KB LDS
// -> 2 blocks/CU (write/compute overlap). Same K-order as v6 (bit-identical).
__global__ __launch_bounds__(256, 4) void k_pv(const unsigned short* __restrict__ P,
                                               const unsigned short* __restrict__ VT,
                                               float* __restrict__ out) {
  __shared__ unsigned short lds[32768];  // 64 KB; regions [b][kh]: 8192 shorts
  const int tid = threadIdx.x;
  const int l = tid & 63, w = tid >> 6;  // 4 waves
  const int wr = w >> 1, wc = w & 1;     // wave grid 2 x 2, each 64x64 out
  const int g = l >> 4, c16 = l & 15;

  // XCD-aware bijective swizzle (4096 % 8 == 0)
  const int bid = blockIdx.x;
  const int x = (bid & 7) * 512 + (bid >> 3);
  const int brow = (x >> 5) * 128;   // 128 row-tiles
  const int bcol = (x & 31) * 128;   // 32 col-tiles

  const int lr_base = w * 16 + (l >> 2);  // + i*64 -> local row 0..127
  const int p = l & 3;

  f32x4 acc[4][4] = {};

#define STAGE(t, kh, b)                                                        \
  {                                                                            \
    const int kofs = (t) * 64 + (kh) * 32;                                     \
    _Pragma("unroll")                                                          \
    for (int i = 0; i < 2; ++i) {                                              \
      int lr = i * 64 + lr_base;                                               \
      int gs = p ^ ((lr >> 1) & 3);                                            \
      unsigned short* dA = lds + ((b) * 2 + (kh)) * 8192 + (i * 256 + w * 64) * 8; \
      async16(P + (size_t)(brow + lr) * 512 + kofs + gs * 8, dA);              \
      async16(VT + (size_t)(bcol + lr) * 512 + kofs + gs * 8, dA + 4096);      \
    }                                                                          \
  }

#define FRAGS(b, kh)                                                           \
  const unsigned short* rbase = lds + ((b) * 2 + (kh)) * 8192;                 \
  bf16x8 a[4], bb[4];                                                          \
  _Pragma("unroll")                                                            \
  for (int mi = 0; mi < 4; ++mi) {                                             \
    int ar = wr * 64 + mi * 16 + c16;                                          \
    a[mi] = *reinterpret_cast<const bf16x8*>(rbase + ar * 32 +                 \
                                             (g ^ ((ar >> 1) & 3)) * 8);       \
  }                                                                            \
  _Pragma("unroll")                                                            \
  for (int nj = 0; nj < 4; ++nj) {                                             \
    int br = wc * 64 + nj * 16 + c16;                                          \
    bb[nj] = *reinterpret_cast<const bf16x8*>(rbase + 4096 + br * 32 +         \
                                              (g ^ ((br >> 1) & 3)) * 8);      \
  }

#define MFMA16()                                                               \
  __builtin_amdgcn_s_setprio(1);                                               \
  _Pragma("unroll")                                                            \
  for (int mi = 0; mi < 4; ++mi)                                               \
    _Pragma("unroll")                                                          \
    for (int nj = 0; nj < 4; ++nj)                                             \
      acc[mi][nj] = __builtin_amdgcn_mfma_f32_16x16x32_bf16(a[mi], bb[nj],     \
                                                            acc[mi][nj], 0, 0, 0); \
  __builtin_amdgcn_s_setprio(0);

  // prologue: 12 loads in flight (t0 kh0, t0 kh1, t1 kh0)
  STAGE(0, 0, 0) STAGE(0, 1, 0) STAGE(1, 0, 1)

  for (int t = 0; t < 7; ++t) {
    const int cur = t & 1, nxt = cur ^ 1;
    asm volatile("s_waitcnt vmcnt(8)" ::: "memory");   // t kh0 staged
    __builtin_amdgcn_s_barrier();
    STAGE(t + 1, 1, nxt)                               // -> 12 in flight
    {
      FRAGS(cur, 0)
      MFMA16()
    }
    asm volatile("s_waitcnt vmcnt(8)" ::: "memory");   // t kh1 staged
    __builtin_amdgcn_s_barrier();
    if (t < 6) STAGE(t + 2, 0, cur)
    {
      FRAGS(cur, 1)
      MFMA16()
    }
  }
  // tail t=7 (cur=1): 8 outstanding
  asm volatile("s_waitcnt vmcnt(4)" ::: "memory");
  __builtin_amdgcn_s_barrier();
  {
    FRAGS(1, 0)
    MFMA16()
  }
  asm volatile("s_waitcnt vmcnt(0)" ::: "memory");
  __builtin_amdgcn_s_barrier();
  {
    FRAGS(1, 1)
    MFMA16()
  }
#undef STAGE
#undef FRAGS
#undef MFMA16

  // C/D layout (validated r4): col = lane&15, row = (lane>>4)*4 + reg
#pragma unroll
  for (int i = 0; i < 4; ++i)
#pragma unroll
    for (int r = 0; r < 4; ++r) {
      const size_t row = (size_t)(brow + wr * 64 + i * 16 + g * 4 + r);
      float* o = out + row * 4096 + bcol + wc * 64 + c16;
#pragma unroll
      for (int j = 0; j < 4; ++j) o[j * 16] = acc[i][j][r];
    }
}

// ---------- launch ----------
extern "C" void kernel_launch(void* const* d_in, const int* in_sizes, int n_in,
                              void* d_out, int out_size, void* d_ws, size_t ws_size,
                              hipStream_t stream) {
  (void)in_sizes; (void)n_in; (void)out_size; (void)ws_size;
  const float* in1   = (const float*)d_in[0];   // [16384][512]
  const float* in2   = (const float*)d_in[1];   // [512][512]
  const float* value = (const float*)d_in[2];   // [512][4096]
  float* out = (float*)d_out;                   // [16384][4096]

  unsigned short* vT   = (unsigned short*)d_ws;  // 4 MB   [4096][512] bf16
  unsigned short* Pb   = vT + 2097152;           // 16 MB  [16384][512] bf16
  unsigned short* in2b = Pb + 8388608;           // 0.5 MB [512][512] bf16

  k_vt<<<dim3(128, 16), dim3(256), 0, stream>>>(value, vT);
  k_cast<<<dim3(256), dim3(256), 0, stream>>>(in2, in2b, 65536);
  k_qk<<<dim3(256), dim3(512), 0, stream>>>(in1, in2b, Pb);
  k_pv<<<dim3(4096), dim3(256), 0, stream>>>(Pb, vT, out);
}

// Round 21
// 170.894 us; speedup vs baseline: 1.1026x; 1.1026x over previous
//
#include <hip/hip_runtime.h>
#include <stdint.h>

// r21: r19 exact config (159.1us best: prep 5 + qk v9 49 + pv v6 105) with ONE
// low-risk lever: pv C-writes via __builtin_nontemporal_store (nt flag) so the
// 268MB output stream doesn't evict P/vT from L2 (512MB of L2-tier re-reads).
// Everything else byte-identical to r19. Ledger: pv = dur - 54.

// ---------- types ----------
typedef __bf16 bf16x8 __attribute__((ext_vector_type(8)));
typedef unsigned short u16x8 __attribute__((ext_vector_type(8)));
typedef float f32x4 __attribute__((ext_vector_type(4)));

#define SM_SCALE 4.419417382415922e-02f /* 1/22.627416997969522 */
#define DROP_SCALE (1.0f / 0.9f)

// ---------- helpers ----------
__device__ __forceinline__ unsigned short f2bf(float f) {
  uint32_t u = __float_as_uint(f);
  uint32_t r = (u + 0x7FFFu + ((u >> 16) & 1u)) >> 16;  // RNE
  return (unsigned short)r;
}
__device__ __forceinline__ float bf2f(unsigned short h) {
  return __uint_as_float(((uint32_t)h) << 16);
}

// async global->LDS, 16B/lane. LDS dest = wave-uniform base + lane*16.
__device__ __forceinline__ void async16(const void* g, void* l) {
  __builtin_amdgcn_global_load_lds(
      (__attribute__((address_space(1))) uint32_t*)g,
      (__attribute__((address_space(3))) uint32_t*)l, 16, 0, 0);
}

// JAX threefry2x32 with key (0,42). [validated r4]
__device__ __forceinline__ void threefry2x32(uint32_t x0, uint32_t x1,
                                             uint32_t& o0, uint32_t& o1) {
  const uint32_t K0 = 0u, K1 = 42u;
  const uint32_t K2 = K0 ^ K1 ^ 0x1BD11BDAu;
  x0 += K0; x1 += K1;
#define TF_R(rot) { x0 += x1; x1 = (x1 << rot) | (x1 >> (32 - rot)); x1 ^= x0; }
  TF_R(13) TF_R(15) TF_R(26) TF_R(6)  x0 += K1; x1 += K2 + 1u;
  TF_R(17) TF_R(29) TF_R(16) TF_R(24) x0 += K2; x1 += K0 + 2u;
  TF_R(13) TF_R(15) TF_R(26) TF_R(6)  x0 += K0; x1 += K1 + 3u;
  TF_R(17) TF_R(29) TF_R(16) TF_R(24) x0 += K1; x1 += K2 + 4u;
  TF_R(13) TF_R(15) TF_R(26) TF_R(6)  x0 += K2; x1 += K0 + 5u;
#undef TF_R
  o0 = x0; o1 = x1;
}

// keep-mask, JAX partitionable threefry, ctr=(0,idx), XOR-fold. [validated r4]
__device__ __forceinline__ bool drop_keep(uint32_t idx) {
  uint32_t o0, o1;
  threefry2x32(0u, idx, o0, o1);
  uint32_t bits = o0 ^ o1;
  float u = __uint_as_float((bits >> 9) | 0x3f800000u) - 1.0f;  // [0,1)
  return u < 0.9f;
}

// ---------- kernel 1: value[512][4096] f32 -> valueT[4096][512] bf16 [validated r4] ----
__global__ __launch_bounds__(256) void k_vt(const float* __restrict__ v,
                                            unsigned short* __restrict__ vt) {
  __shared__ float tile[32][33];
  const int nb = blockIdx.x;   // 0..127
  const int kb = blockIdx.y;   // 0..15
  const int tx = threadIdx.x & 31, ty = threadIdx.x >> 5;  // 32 x 8
#pragma unroll
  for (int yy = 0; yy < 4; ++yy) {
    int row = ty + yy * 8;
    tile[row][tx] = v[(size_t)(kb * 32 + row) * 4096 + nb * 32 + tx];
  }
  __syncthreads();
#pragma unroll
  for (int yy = 0; yy < 4; ++yy) {
    int row = ty + yy * 8;
    vt[(size_t)(nb * 32 + row) * 512 + kb * 32 + tx] = f2bf(tile[tx][row]);
  }
}

// ---------- kernel 1b: in2 f32 -> bf16 (RNE) [validated r9] ----------
__global__ __launch_bounds__(256) void k_cast(const float* __restrict__ src,
                                              unsigned short* __restrict__ dst,
                                              int n4) {
  int i = blockIdx.x * 256 + threadIdx.x;
  if (i >= n4) return;
  float4 v = reinterpret_cast<const float4*>(src)[i];
  ushort4 h;
  h.x = f2bf(v.x); h.y = f2bf(v.y); h.z = f2bf(v.z); h.w = f2bf(v.w);
  reinterpret_cast<ushort4*>(dst)[i] = h;
}

// ---------- kernel 2: QK^T (A-split bf16 MFMA, 2-term) + softmax + dropout -> P ----
// [v9 exact bytes — r19, measured 49us]
__global__ __launch_bounds__(512, 4) void k_qk(const float* __restrict__ in1,
                                               const unsigned short* __restrict__ B2,
                                               unsigned short* __restrict__ P) {
  __shared__ unsigned short lB[512][36];  // 36.9KB, 72B stride -> conflict-free
  __shared__ float redm[2][64], reds[2][64];

  const int tid = threadIdx.x;
  const int l = tid & 63, w = tid >> 6;
  const int wr = w >> 1, wc = w & 1;      // wave grid 4 x 2
  const int g = l >> 4, c16 = l & 15;
  const int brow = blockIdx.x * 64;

  int scol[4], ssub[4];
#pragma unroll
  for (int i = 0; i < 4; ++i) {
    int c = i * 512 + tid;
    scol[i] = c >> 2;
    ssub[i] = c & 3;
  }

  f32x4 acc[16] = {};
  u16x8 stB[4];

#pragma unroll
  for (int i = 0; i < 4; ++i)
    stB[i] = *reinterpret_cast<const u16x8*>(B2 + (size_t)scol[i] * 512 + ssub[i] * 8);

  for (int kt = 0; kt < 16; ++kt) {
    const int k0 = kt * 32;
#pragma unroll
    for (int i = 0; i < 4; ++i)
      *reinterpret_cast<u16x8*>(&lB[scol[i]][ssub[i] * 8]) = stB[i];
    const int arow = brow + wr * 16 + c16;
    float4 v0 = *reinterpret_cast<const float4*>(in1 + (size_t)arow * 512 + k0 + g * 8);
    float4 v1 = *reinterpret_cast<const float4*>(in1 + (size_t)arow * 512 + k0 + g * 8 + 4);
    bf16x8 ahi, alo;
    {
      float vv[8] = {v0.x, v0.y, v0.z, v0.w, v1.x, v1.y, v1.z, v1.w};
      unsigned short h[8], lo8[8];
#pragma unroll
      for (int e = 0; e < 8; ++e) {
        h[e] = f2bf(vv[e]);
        lo8[e] = f2bf(vv[e] - bf2f(h[e]));
      }
      ahi = *reinterpret_cast<const bf16x8*>(h);
      alo = *reinterpret_cast<const bf16x8*>(lo8);
    }
    __syncthreads();
    if (kt < 15) {
      const int kn = k0 + 32;
#pragma unroll
      for (int i = 0; i < 4; ++i)
        stB[i] = *reinterpret_cast<const u16x8*>(B2 + (size_t)scol[i] * 512 + kn + ssub[i] * 8);
    }
#pragma unroll
    for (int j = 0; j < 16; ++j) {
      const int col = wc * 256 + j * 16 + c16;
      bf16x8 bh = *reinterpret_cast<const bf16x8*>(&lB[col][g * 8]);
      acc[j] = __builtin_amdgcn_mfma_f32_16x16x32_bf16(ahi, bh, acc[j], 0, 0, 0);
      acc[j] = __builtin_amdgcn_mfma_f32_16x16x32_bf16(alo, bh, acc[j], 0, 0, 0);
    }
    __syncthreads();
  }

  const int rowbase = wr * 16 + g * 4;
  float mx[4] = {-3.4e38f, -3.4e38f, -3.4e38f, -3.4e38f};
#pragma unroll
  for (int j = 0; j < 16; ++j)
#pragma unroll
    for (int r = 0; r < 4; ++r) {
      acc[j][r] *= SM_SCALE;
      mx[r] = fmaxf(mx[r], acc[j][r]);
    }
#pragma unroll
  for (int s = 1; s < 16; s <<= 1)
#pragma unroll
    for (int r = 0; r < 4; ++r) mx[r] = fmaxf(mx[r], __shfl_xor(mx[r], s, 64));
  if (c16 == 0) {
#pragma unroll
    for (int r = 0; r < 4; ++r) redm[wc][rowbase + r] = mx[r];
  }
  __syncthreads();
  float rmax[4], sum[4] = {0.f, 0.f, 0.f, 0.f};
#pragma unroll
  for (int r = 0; r < 4; ++r)
    rmax[r] = fmaxf(redm[0][rowbase + r], redm[1][rowbase + r]);
#pragma unroll
  for (int j = 0; j < 16; ++j)
#pragma unroll
    for (int r = 0; r < 4; ++r) {
      float e = expf(acc[j][r] - rmax[r]);
      acc[j][r] = e;
      sum[r] += e;
    }
#pragma unroll
  for (int s = 1; s < 16; s <<= 1)
#pragma unroll
    for (int r = 0; r < 4; ++r) sum[r] += __shfl_xor(sum[r], s, 64);
  if (c16 == 0) {
#pragma unroll
    for (int r = 0; r < 4; ++r) reds[wc][rowbase + r] = sum[r];
  }
  __syncthreads();
  float scl[4];
#pragma unroll
  for (int r = 0; r < 4; ++r)
    scl[r] = DROP_SCALE / (reds[0][rowbase + r] + reds[1][rowbase + r]);

#pragma unroll
  for (int j = 0; j < 16; ++j) {
    const int col = wc * 256 + j * 16 + c16;
#pragma unroll
    for (int r = 0; r < 4; ++r) {
      uint32_t idx = (uint32_t)(brow + rowbase + r) * 512u + (uint32_t)col;
      float pv = drop_keep(idx) ? acc[j][r] * scl[r] : 0.0f;
      P[idx] = f2bf(pv);
    }
  }
}

// ---------- kernel 3: out = P[16384][512] @ vT[4096][512]^T (bf16 MFMA) ----------
// v6 (r15 bytes) + nontemporal C-stores (only change: epilogue store intrinsic).
__global__ __launch_bounds__(512) void k_pv(const unsigned short* __restrict__ P,
                                            const unsigned short* __restrict__ VT,
                                            float* __restrict__ out) {
  __shared__ unsigned short lds[65536];  // 128 KB
  const int tid = threadIdx.x;
  const int l = tid & 63, w = tid >> 6;
  const int wr = w >> 2, wc = w & 3;     // wave grid 2(M) x 4(N)
  const int g = l >> 4, c16 = l & 15;

  const int bid = blockIdx.x;
  const int x = (bid & 7) * 128 + (bid >> 3);
  const int brow = (x >> 4) * 256;   // 64 row-panels
  const int bcol = (x & 15) * 256;   // 16 col-panels

  const int lr_base = w * 16 + (l >> 2);
  const int p = l & 3;

  f32x4 acc[8][4] = {};

#define STAGE(t, kh, b)                                                        \
  {                                                                            \
    const int kofs = (t) * 64 + (kh) * 32;                                     \
    _Pragma("unroll")                                                          \
    for (int i = 0; i < 2; ++i) {                                              \
      int lr = i * 128 + lr_base;                                              \
      int gs = p ^ ((lr >> 1) & 3);                                            \
      unsigned short* dA = lds + ((b) * 2 + (kh)) * 8192 + (i * 512 + w * 64) * 8; \
      async16(P + (size_t)(brow + lr) * 512 + kofs + gs * 8, dA);              \
      async16(VT + (size_t)(bcol + lr) * 512 + kofs + gs * 8, dA + 32768);     \
    }                                                                          \
  }

#define FRAGS(b, kh)                                                           \
  const unsigned short* rbase = lds + ((b) * 2 + (kh)) * 8192;                 \
  bf16x8 a[8], bb[4];                                                          \
  _Pragma("unroll")                                                            \
  for (int mi = 0; mi < 8; ++mi) {                                             \
    int ar = wr * 128 + mi * 16 + c16;                                         \
    a[mi] = *reinterpret_cast<const bf16x8*>(rbase + ar * 32 +                 \
                                             (g ^ ((ar >> 1) & 3)) * 8);       \
  }                                                                            \
  _Pragma("unroll")                                                            \
  for (int nj = 0; nj < 4; ++nj) {                                             \
    int br = wc * 64 + nj * 16 + c16;                                          \
    bb[nj] = *reinterpret_cast<const bf16x8*>(rbase + 32768 + br * 32 +        \
                                              (g ^ ((br >> 1) & 3)) * 8);      \
  }

#define MFMA32()                                                               \
  __builtin_amdgcn_s_setprio(1);                                               \
  _Pragma("unroll")                                                            \
  for (int mi = 0; mi < 8; ++mi)                                               \
    _Pragma("unroll")                                                          \
    for (int nj = 0; nj < 4; ++nj)                                             \
      acc[mi][nj] = __builtin_amdgcn_mfma_f32_16x16x32_bf16(a[mi], bb[nj],     \
                                                            acc[mi][nj], 0, 0, 0); \
  __builtin_amdgcn_s_setprio(0);

  STAGE(0, 0, 0) STAGE(0, 1, 0) STAGE(1, 0, 1)

  for (int t = 0; t < 7; ++t) {
    const int cur = t & 1, nxt = cur ^ 1;
    asm volatile("s_waitcnt vmcnt(8)" ::: "memory");
    __builtin_amdgcn_s_barrier();
    STAGE(t + 1, 1, nxt)
    {
      FRAGS(cur, 0)
      MFMA32()
    }
    asm volatile("s_waitcnt vmcnt(8)" ::: "memory");
    __builtin_amdgcn_s_barrier();
    if (t < 6) STAGE(t + 2, 0, cur)
    {
      FRAGS(cur, 1)
      MFMA32()
    }
  }
  asm volatile("s_waitcnt vmcnt(4)" ::: "memory");
  __builtin_amdgcn_s_barrier();
  {
    FRAGS(1, 0)
    MFMA32()
  }
  asm volatile("s_waitcnt vmcnt(0)" ::: "memory");
  __builtin_amdgcn_s_barrier();
  {
    FRAGS(1, 1)
    MFMA32()
  }
#undef STAGE
#undef FRAGS
#undef MFMA32

  // C/D layout (validated r4): col = lane&15, row = (lane>>4)*4 + reg
  // nontemporal stores: keep 268MB output stream out of L2 (P/vT stay hot).
#pragma unroll
  for (int i = 0; i < 8; ++i)
#pragma unroll
    for (int r = 0; r < 4; ++r) {
      const size_t row = (size_t)(brow + wr * 128 + i * 16 + g * 4 + r);
      float* o = out + row * 4096 + bcol + wc * 64 + c16;
#pragma unroll
      for (int j = 0; j < 4; ++j)
        __builtin_nontemporal_store(acc[i][j][r], o + j * 16);
    }
}

// ---------- launch ----------
extern "C" void kernel_launch(void* const* d_in, const int* in_sizes, int n_in,
                              void* d_out, int out_size, void* d_ws, size_t ws_size,
                              hipStream_t stream) {
  (void)in_sizes; (void)n_in; (void)out_size; (void)ws_size;
  const float* in1   = (const float*)d_in[0];   // [16384][512]
  const float* in2   = (const float*)d_in[1];   // [512][512]
  const float* value = (const float*)d_in[2];   // [512][4096]
  float* out = (float*)d_out;                   // [16384][4096]

  unsigned short* vT   = (unsigned short*)d_ws;  // 4 MB   [4096][512] bf16
  unsigned short* Pb   = vT + 2097152;           // 16 MB  [16384][512] bf16
  unsigned short* in2b = Pb + 8388608;           // 0.5 MB [512][512] bf16

  k_vt<<<dim3(128, 16), dim3(256), 0, stream>>>(value, vT);
  k_cast<<<dim3(256), dim3(256), 0, stream>>>(in2, in2b, 65536);
  k_qk<<<dim3(256), dim3(512), 0, stream>>>(in1, in2b, Pb);
  k_pv<<<dim3(1024), dim3(512), 0, stream>>>(Pb, vT, out);
}

// Round 22
// 158.801 us; speedup vs baseline: 1.1866x; 1.0761x over previous
//
#include <hip/hip_runtime.h>
#include <stdint.h>

// r22: LOCK-IN = r19 exact source (session best, 159.1us).
// prep ~5 (k_vt + k_cast), qk v9 ~49 (64-row, 2-term A-split, lb(512,4),
// T14 reg-prefetch of B(kt+1) under MFMA), pv v6 ~105 (256x256, counted-vmcnt
// k-half pipeline: 12 loads in flight, waits at vmcnt(8), setprio clusters).
// r21's nontemporal C-stores regressed (105->117): nt bypasses L2
// write-combining; reverted.

// ---------- types ----------
typedef __bf16 bf16x8 __attribute__((ext_vector_type(8)));
typedef unsigned short u16x8 __attribute__((ext_vector_type(8)));
typedef float f32x4 __attribute__((ext_vector_type(4)));

#define SM_SCALE 4.419417382415922e-02f /* 1/22.627416997969522 */
#define DROP_SCALE (1.0f / 0.9f)

// ---------- helpers ----------
__device__ __forceinline__ unsigned short f2bf(float f) {
  uint32_t u = __float_as_uint(f);
  uint32_t r = (u + 0x7FFFu + ((u >> 16) & 1u)) >> 16;  // RNE
  return (unsigned short)r;
}
__device__ __forceinline__ float bf2f(unsigned short h) {
  return __uint_as_float(((uint32_t)h) << 16);
}

// async global->LDS, 16B/lane. LDS dest = wave-uniform base + lane*16.
__device__ __forceinline__ void async16(const void* g, void* l) {
  __builtin_amdgcn_global_load_lds(
      (__attribute__((address_space(1))) uint32_t*)g,
      (__attribute__((address_space(3))) uint32_t*)l, 16, 0, 0);
}

// JAX threefry2x32 with key (0,42). [validated r4]
__device__ __forceinline__ void threefry2x32(uint32_t x0, uint32_t x1,
                                             uint32_t& o0, uint32_t& o1) {
  const uint32_t K0 = 0u, K1 = 42u;
  const uint32_t K2 = K0 ^ K1 ^ 0x1BD11BDAu;
  x0 += K0; x1 += K1;
#define TF_R(rot) { x0 += x1; x1 = (x1 << rot) | (x1 >> (32 - rot)); x1 ^= x0; }
  TF_R(13) TF_R(15) TF_R(26) TF_R(6)  x0 += K1; x1 += K2 + 1u;
  TF_R(17) TF_R(29) TF_R(16) TF_R(24) x0 += K2; x1 += K0 + 2u;
  TF_R(13) TF_R(15) TF_R(26) TF_R(6)  x0 += K0; x1 += K1 + 3u;
  TF_R(17) TF_R(29) TF_R(16) TF_R(24) x0 += K1; x1 += K2 + 4u;
  TF_R(13) TF_R(15) TF_R(26) TF_R(6)  x0 += K2; x1 += K0 + 5u;
#undef TF_R
  o0 = x0; o1 = x1;
}

// keep-mask, JAX partitionable threefry, ctr=(0,idx), XOR-fold. [validated r4]
__device__ __forceinline__ bool drop_keep(uint32_t idx) {
  uint32_t o0, o1;
  threefry2x32(0u, idx, o0, o1);
  uint32_t bits = o0 ^ o1;
  float u = __uint_as_float((bits >> 9) | 0x3f800000u) - 1.0f;  // [0,1)
  return u < 0.9f;
}

// ---------- kernel 1: value[512][4096] f32 -> valueT[4096][512] bf16 [validated r4] ----
__global__ __launch_bounds__(256) void k_vt(const float* __restrict__ v,
                                            unsigned short* __restrict__ vt) {
  __shared__ float tile[32][33];
  const int nb = blockIdx.x;   // 0..127
  const int kb = blockIdx.y;   // 0..15
  const int tx = threadIdx.x & 31, ty = threadIdx.x >> 5;  // 32 x 8
#pragma unroll
  for (int yy = 0; yy < 4; ++yy) {
    int row = ty + yy * 8;
    tile[row][tx] = v[(size_t)(kb * 32 + row) * 4096 + nb * 32 + tx];
  }
  __syncthreads();
#pragma unroll
  for (int yy = 0; yy < 4; ++yy) {
    int row = ty + yy * 8;
    vt[(size_t)(nb * 32 + row) * 512 + kb * 32 + tx] = f2bf(tile[tx][row]);
  }
}

// ---------- kernel 1b: in2 f32 -> bf16 (RNE) [validated r9] ----------
__global__ __launch_bounds__(256) void k_cast(const float* __restrict__ src,
                                              unsigned short* __restrict__ dst,
                                              int n4) {
  int i = blockIdx.x * 256 + threadIdx.x;
  if (i >= n4) return;
  float4 v = reinterpret_cast<const float4*>(src)[i];
  ushort4 h;
  h.x = f2bf(v.x); h.y = f2bf(v.y); h.z = f2bf(v.z); h.w = f2bf(v.w);
  reinterpret_cast<ushort4*>(dst)[i] = h;
}

// ---------- kernel 2: QK^T (A-split bf16 MFMA, 2-term) + softmax + dropout -> P ----
// [v9 — r19, measured 49us]
__global__ __launch_bounds__(512, 4) void k_qk(const float* __restrict__ in1,
                                               const unsigned short* __restrict__ B2,
                                               unsigned short* __restrict__ P) {
  __shared__ unsigned short lB[512][36];  // 36.9KB, 72B stride -> conflict-free
  __shared__ float redm[2][64], reds[2][64];

  const int tid = threadIdx.x;
  const int l = tid & 63, w = tid >> 6;
  const int wr = w >> 1, wc = w & 1;      // wave grid 4 x 2
  const int g = l >> 4, c16 = l & 15;
  const int brow = blockIdx.x * 64;

  int scol[4], ssub[4];
#pragma unroll
  for (int i = 0; i < 4; ++i) {
    int c = i * 512 + tid;
    scol[i] = c >> 2;
    ssub[i] = c & 3;
  }

  f32x4 acc[16] = {};
  u16x8 stB[4];

#pragma unroll
  for (int i = 0; i < 4; ++i)
    stB[i] = *reinterpret_cast<const u16x8*>(B2 + (size_t)scol[i] * 512 + ssub[i] * 8);

  for (int kt = 0; kt < 16; ++kt) {
    const int k0 = kt * 32;
#pragma unroll
    for (int i = 0; i < 4; ++i)
      *reinterpret_cast<u16x8*>(&lB[scol[i]][ssub[i] * 8]) = stB[i];
    const int arow = brow + wr * 16 + c16;
    float4 v0 = *reinterpret_cast<const float4*>(in1 + (size_t)arow * 512 + k0 + g * 8);
    float4 v1 = *reinterpret_cast<const float4*>(in1 + (size_t)arow * 512 + k0 + g * 8 + 4);
    bf16x8 ahi, alo;
    {
      float vv[8] = {v0.x, v0.y, v0.z, v0.w, v1.x, v1.y, v1.z, v1.w};
      unsigned short h[8], lo8[8];
#pragma unroll
      for (int e = 0; e < 8; ++e) {
        h[e] = f2bf(vv[e]);
        lo8[e] = f2bf(vv[e] - bf2f(h[e]));
      }
      ahi = *reinterpret_cast<const bf16x8*>(h);
      alo = *reinterpret_cast<const bf16x8*>(lo8);
    }
    __syncthreads();
    if (kt < 15) {
      const int kn = k0 + 32;
#pragma unroll
      for (int i = 0; i < 4; ++i)
        stB[i] = *reinterpret_cast<const u16x8*>(B2 + (size_t)scol[i] * 512 + kn + ssub[i] * 8);
    }
#pragma unroll
    for (int j = 0; j < 16; ++j) {
      const int col = wc * 256 + j * 16 + c16;
      bf16x8 bh = *reinterpret_cast<const bf16x8*>(&lB[col][g * 8]);
      acc[j] = __builtin_amdgcn_mfma_f32_16x16x32_bf16(ahi, bh, acc[j], 0, 0, 0);
      acc[j] = __builtin_amdgcn_mfma_f32_16x16x32_bf16(alo, bh, acc[j], 0, 0, 0);
    }
    __syncthreads();
  }

  const int rowbase = wr * 16 + g * 4;
  float mx[4] = {-3.4e38f, -3.4e38f, -3.4e38f, -3.4e38f};
#pragma unroll
  for (int j = 0; j < 16; ++j)
#pragma unroll
    for (int r = 0; r < 4; ++r) {
      acc[j][r] *= SM_SCALE;
      mx[r] = fmaxf(mx[r], acc[j][r]);
    }
#pragma unroll
  for (int s = 1; s < 16; s <<= 1)
#pragma unroll
    for (int r = 0; r < 4; ++r) mx[r] = fmaxf(mx[r], __shfl_xor(mx[r], s, 64));
  if (c16 == 0) {
#pragma unroll
    for (int r = 0; r < 4; ++r) redm[wc][rowbase + r] = mx[r];
  }
  __syncthreads();
  float rmax[4], sum[4] = {0.f, 0.f, 0.f, 0.f};
#pragma unroll
  for (int r = 0; r < 4; ++r)
    rmax[r] = fmaxf(redm[0][rowbase + r], redm[1][rowbase + r]);
#pragma unroll
  for (int j = 0; j < 16; ++j)
#pragma unroll
    for (int r = 0; r < 4; ++r) {
      float e = expf(acc[j][r] - rmax[r]);
      acc[j][r] = e;
      sum[r] += e;
    }
#pragma unroll
  for (int s = 1; s < 16; s <<= 1)
#pragma unroll
    for (int r = 0; r < 4; ++r) sum[r] += __shfl_xor(sum[r], s, 64);
  if (c16 == 0) {
#pragma unroll
    for (int r = 0; r < 4; ++r) reds[wc][rowbase + r] = sum[r];
  }
  __syncthreads();
  float scl[4];
#pragma unroll
  for (int r = 0; r < 4; ++r)
    scl[r] = DROP_SCALE / (reds[0][rowbase + r] + reds[1][rowbase + r]);

#pragma unroll
  for (int j = 0; j < 16; ++j) {
    const int col = wc * 256 + j * 16 + c16;
#pragma unroll
    for (int r = 0; r < 4; ++r) {
      uint32_t idx = (uint32_t)(brow + rowbase + r) * 512u + (uint32_t)col;
      float pv = drop_keep(idx) ? acc[j][r] * scl[r] : 0.0f;
      P[idx] = f2bf(pv);
    }
  }
}

// ---------- kernel 3: out = P[16384][512] @ vT[4096][512]^T (bf16 MFMA) ----------
// [v6 — r15/r16/r19, counted-vmcnt k-half pipeline, ~105us]
__global__ __launch_bounds__(512) void k_pv(const unsigned short* __restrict__ P,
                                            const unsigned short* __restrict__ VT,
                                            float* __restrict__ out) {
  __shared__ unsigned short lds[65536];  // 128 KB
  const int tid = threadIdx.x;
  const int l = tid & 63, w = tid >> 6;
  const int wr = w >> 2, wc = w & 3;     // wave grid 2(M) x 4(N)
  const int g = l >> 4, c16 = l & 15;

  const int bid = blockIdx.x;
  const int x = (bid & 7) * 128 + (bid >> 3);
  const int brow = (x >> 4) * 256;   // 64 row-panels
  const int bcol = (x & 15) * 256;   // 16 col-panels

  const int lr_base = w * 16 + (l >> 2);
  const int p = l & 3;

  f32x4 acc[8][4] = {};

#define STAGE(t, kh, b)                                                        \
  {                                                                            \
    const int kofs = (t) * 64 + (kh) * 32;                                     \
    _Pragma("unroll")                                                          \
    for (int i = 0; i < 2; ++i) {                                              \
      int lr = i * 128 + lr_base;                                              \
      int gs = p ^ ((lr >> 1) & 3);                                            \
      unsigned short* dA = lds + ((b) * 2 + (kh)) * 8192 + (i * 512 + w * 64) * 8; \
      async16(P + (size_t)(brow + lr) * 512 + kofs + gs * 8, dA);              \
      async16(VT + (size_t)(bcol + lr) * 512 + kofs + gs * 8, dA + 32768);     \
    }                                                                          \
  }

#define FRAGS(b, kh)                                                           \
  const unsigned short* rbase = lds + ((b) * 2 + (kh)) * 8192;                 \
  bf16x8 a[8], bb[4];                                                          \
  _Pragma("unroll")                                                            \
  for (int mi = 0; mi < 8; ++mi) {                                             \
    int ar = wr * 128 + mi * 16 + c16;                                         \
    a[mi] = *reinterpret_cast<const bf16x8*>(rbase + ar * 32 +                 \
                                             (g ^ ((ar >> 1) & 3)) * 8);       \
  }                                                                            \
  _Pragma("unroll")                                                            \
  for (int nj = 0; nj < 4; ++nj) {                                             \
    int br = wc * 64 + nj * 16 + c16;                                          \
    bb[nj] = *reinterpret_cast<const bf16x8*>(rbase + 32768 + br * 32 +        \
                                              (g ^ ((br >> 1) & 3)) * 8);      \
  }

#define MFMA32()                                                               \
  __builtin_amdgcn_s_setprio(1);                                               \
  _Pragma("unroll")                                                            \
  for (int mi = 0; mi < 8; ++mi)                                               \
    _Pragma("unroll")                                                          \
    for (int nj = 0; nj < 4; ++nj)                                             \
      acc[mi][nj] = __builtin_amdgcn_mfma_f32_16x16x32_bf16(a[mi], bb[nj],     \
                                                            acc[mi][nj], 0, 0, 0); \
  __builtin_amdgcn_s_setprio(0);

  STAGE(0, 0, 0) STAGE(0, 1, 0) STAGE(1, 0, 1)

  for (int t = 0; t < 7; ++t) {
    const int cur = t & 1, nxt = cur ^ 1;
    asm volatile("s_waitcnt vmcnt(8)" ::: "memory");
    __builtin_amdgcn_s_barrier();
    STAGE(t + 1, 1, nxt)
    {
      FRAGS(cur, 0)
      MFMA32()
    }
    asm volatile("s_waitcnt vmcnt(8)" ::: "memory");
    __builtin_amdgcn_s_barrier();
    if (t < 6) STAGE(t + 2, 0, cur)
    {
      FRAGS(cur, 1)
      MFMA32()
    }
  }
  asm volatile("s_waitcnt vmcnt(4)" ::: "memory");
  __builtin_amdgcn_s_barrier();
  {
    FRAGS(1, 0)
    MFMA32()
  }
  asm volatile("s_waitcnt vmcnt(0)" ::: "memory");
  __builtin_amdgcn_s_barrier();
  {
    FRAGS(1, 1)
    MFMA32()
  }
#undef STAGE
#undef FRAGS
#undef MFMA32

  // C/D layout (validated r4): col = lane&15, row = (lane>>4)*4 + reg
#pragma unroll
  for (int i = 0; i < 8; ++i)
#pragma unroll
    for (int r = 0; r < 4; ++r) {
      const size_t row = (size_t)(brow + wr * 128 + i * 16 + g * 4 + r);
      float* o = out + row * 4096 + bcol + wc * 64 + c16;
#pragma unroll
      for (int j = 0; j < 4; ++j) o[j * 16] = acc[i][j][r];
    }
}

// ---------- launch ----------
extern "C" void kernel_launch(void* const* d_in, const int* in_sizes, int n_in,
                              void* d_out, int out_size, void* d_ws, size_t ws_size,
                              hipStream_t stream) {
  (void)in_sizes; (void)n_in; (void)out_size; (void)ws_size;
  const float* in1   = (const float*)d_in[0];   // [16384][512]
  const float* in2   = (const float*)d_in[1];   // [512][512]
  const float* value = (const float*)d_in[2];   // [512][4096]
  float* out = (float*)d_out;                   // [16384][4096]

  unsigned short* vT   = (unsigned short*)d_ws;  // 4 MB   [4096][512] bf16
  unsigned short* Pb   = vT + 2097152;           // 16 MB  [16384][512] bf16
  unsigned short* in2b = Pb + 8388608;           // 0.5 MB [512][512] bf16

  k_vt<<<dim3(128, 16), dim3(256), 0, stream>>>(value, vT);
  k_cast<<<dim3(256), dim3(256), 0, stream>>>(in2, in2b, 65536);
  k_qk<<<dim3(256), dim3(512), 0, stream>>>(in1, in2b, Pb);
  k_pv<<<dim3(1024), dim3(512), 0, stream>>>(Pb, vT, out);
}